// Round 13
// baseline (323.080 us; speedup 1.0000x reference)
//
#include <hip/hip_runtime.h>
#include <hip/hip_bf16.h>
#include <math.h>

typedef __bf16 bf16;
typedef float f32x4 __attribute__((ext_vector_type(4)));
typedef float f32x16 __attribute__((ext_vector_type(16)));
typedef bf16 bf16x8 __attribute__((ext_vector_type(8)));
typedef bf16 bf16x4 __attribute__((ext_vector_type(4)));
typedef unsigned int uint;
typedef uint uintx2 __attribute__((ext_vector_type(2)));

#define MFMA16(a, b, c) __builtin_amdgcn_mfma_f32_16x16x32_bf16(a, b, c, 0, 0, 0)
#define MFMA32(a, b, c) __builtin_amdgcn_mfma_f32_32x32x16_bf16(a, b, c, 0, 0, 0)

static constexpr int T_SEQ = 2048;
static constexpr int CDIM  = 1024;
static constexpr int NH    = 16;
static constexpr int DH    = 64;
static constexpr float FREQ_C = 0.20762050593045998f;   // log2(10000)/64
// 1/sqrt(64) * log2(e): folded into Q so flash uses bare exp2
static constexpr float Q_SCALE = 0.18033688011112042f;

// raw v_exp_f32 (1 trans op; no denormal-fixup expansion). Safe here: all
// results are normal-range, flush-to-zero unobservable after bf16 cast.
__device__ __forceinline__ float fexp2(float x) {
    return __builtin_amdgcn_exp2f(x);
}

// pack two f32 -> bf16x2 word via scalar casts; compiler fuses to the packed
// cvt with CORRECT operand order. (r11's hand-asm cvt_pk had a different
// packing convention -> pair scramble. Do not hand-write it.)
__device__ __forceinline__ uint pack_bf16(float lo, float hi) {
    union { bf16 h[2]; uint u; } cv;
    cv.h[0] = (bf16)lo;
    cv.h[1] = (bf16)hi;
    return cv.u;
}

// async global->LDS, 16B per lane. LDS dest is wave-uniform base + lane*16.
__device__ __forceinline__ void gld_lds16(const bf16* g, bf16* l) {
    __builtin_amdgcn_global_load_lds(
        (const __attribute__((address_space(1))) void*)g,
        (__attribute__((address_space(3))) void*)l, 16, 0, 0);
}

// Accurate fast sincos: 2-term Cody-Waite reduction to [-pi,pi], then native.
__device__ __forceinline__ void fast_sincos(float x, float* s, float* c) {
    const float INV2PI = 0.15915494309189535f;
    const float PI2_HI = 6.28125f;
    const float PI2_LO = 1.9353071795864769e-3f;
    const float n = rintf(x * INV2PI);
    float r = fmaf(-n, PI2_HI, x);
    r = fmaf(-n, PI2_LO, r);
    *s = __sinf(r);
    *c = __cosf(r);
}

__device__ __forceinline__ void cvt8(const float* __restrict__ in,
                                     bf16* __restrict__ out, int i) {
    const f32x4* p = (const f32x4*)(in + (size_t)i * 8);
    const f32x4 lo = p[0], hi = p[1];
    bf16x8 o;
    o[0] = (bf16)lo[0]; o[1] = (bf16)lo[1]; o[2] = (bf16)lo[2]; o[3] = (bf16)lo[3];
    o[4] = (bf16)hi[0]; o[5] = (bf16)hi[1]; o[6] = (bf16)hi[2]; o[7] = (bf16)hi[3];
    *(bf16x8*)(out + (size_t)i * 8) = o;
}

// ---------------------------------------------------------------------------
// Fused prologue: all 3 fp32->bf16 conversions + RoPE table in ONE launch.
// Block ranges: [0,4096) x | [4096,5632) w_attn | [5632,6144) w_proj |
// [6144,6400) rope table.
// ---------------------------------------------------------------------------
__global__ __launch_bounds__(256)
void prologue(const float* __restrict__ x, const float* __restrict__ wa,
              const float* __restrict__ wp, bf16* __restrict__ Xb,
              bf16* __restrict__ Wab, bf16* __restrict__ Wpb,
              float2* __restrict__ tab) {
    const int b = blockIdx.x, tid = threadIdx.x;
    if (b < 4096) {
        cvt8(x, Xb, b * 256 + tid);
    } else if (b < 5632) {
        cvt8(wa, Wab, (b - 4096) * 256 + tid);
    } else if (b < 6144) {
        cvt8(wp, Wpb, (b - 5632) * 256 + tid);
    } else {
        const int i = (b - 6144) * 256 + tid;       // 2048*32 entries
        const int t = i >> 5, p = i & 31;
        const float ang = (float)t * exp2f(-2.0f * (float)p * FREQ_C);
        float s, c;
        fast_sincos(ang, &s, &c);
        tab[i] = make_float2(c, s);
    }
}

// ---------------------------------------------------------------------------
// QKV GEMM + fused RoPE — 256x256 tile, 8 waves (2M x 4N), 4-phase K-tile
// schedule with counted waits (T3+T4) + setprio (T5). Rationale: seven 128^2
// schedule variants all pinned at 117us (structure floor, 440 TF); the
// catalog's regime gate says T3/T4/T5 pay ONLY in the 256^2 8-wave phase-
// interleaved structure (m230/m218: +28-73%). T2 swizzle is NOT needed: our
// subtile-blocked LDS layout already measures 0 bank conflicts.
//   - per-wave output 128x64: acc[8][4] f32x4 (128 VGPR); launch_bounds(512,2)
//   - LDS 128KB: 2 bufs x (A 32KB + B 32KB), 32 subtiles [16r x 32k] each
//   - per K-tile t (buf=t&1), 4 phases q (kg=q>>1, b-pair=q&1):
//       q==0: s_waitcnt vmcnt(0)   <- my tile-t loads (issued >=2 phases ago)
//       s_barrier + sched_barrier  <- visibility; block ds_read hoist
//       ds_read af[8] (per-kg) / bfr[2] (per-phase)
//       phases 0-1: stage 4 subtiles of tile t+1 into buf^1 (front-loaded)
//       sched_barrier; setprio(1); 16 MFMA; setprio(0)
//   - overwrite-safe: phase-3 lgkm completion precedes next tile's barrier,
//     and t+1 staging is issued only after that barrier.
// Grid 384 = dim3(12,32); XCD-bijective chunked swizzle, bmp-fastest.
// ---------------------------------------------------------------------------
__global__ __launch_bounds__(512, 2)
void gemm_qkv(const bf16* __restrict__ X, const bf16* __restrict__ W,
              bf16* __restrict__ Qo, bf16* __restrict__ Ko, bf16* __restrict__ Vt,
              const float2* __restrict__ tab) {
    __shared__ __align__(16) bf16 ash[2][32 * 512];
    __shared__ __align__(16) bf16 bsh[2][32 * 512];
    const int tid = threadIdx.x, lane = tid & 63, wave = tid >> 6;   // 0..7
    const int quad = lane >> 4, l16 = lane & 15;
    const int wm = wave >> 2, wn = wave & 3;
    const int sm = lane & 15, sc = lane >> 4;
    const int lin = blockIdx.y * 12 + blockIdx.x;        // 0..383
    const int xcd = lin & 7, j = lin >> 3;               // j in [0,48)
    const int bmp = xcd * 4 + (j & 3), bnp = j >> 2;     // bmp [0,32), bnp [0,12)

    const bf16* Abase = X + (size_t)(bmp * 256) * CDIM;
    const bf16* Bbase = W + (size_t)(bnp * 256) * CDIM;

    f32x4 acc[8][4] = {};

    // prologue: stage K-tile 0 into buf 0 (each wave: 4 A + 4 B subtiles)
#pragma unroll
    for (int u = 0; u < 4; u++) {
        const int st = wave * 4 + u, mg = st >> 1, kg = st & 1;
        const size_t off = (size_t)(mg * 16 + sm) * CDIM + kg * 32 + sc * 8;
        gld_lds16(Abase + off, &ash[0][st * 512]);
        gld_lds16(Bbase + off, &bsh[0][st * 512]);
    }

    for (int t = 0; t < 16; t++) {
        const int buf = t & 1;
        bf16x8 af[8];
#pragma unroll
        for (int q = 0; q < 4; q++) {
            const int kg = q >> 1, bp = q & 1;
            if (q == 0) asm volatile("s_waitcnt vmcnt(0)" ::: "memory");
            __builtin_amdgcn_s_barrier();
            __builtin_amdgcn_sched_barrier(0);
            // ds_reads for this phase's MFMA quadrant
            if (bp == 0) {
#pragma unroll
                for (int a = 0; a < 8; a++)
                    af[a] = *(const bf16x8*)
                        &ash[buf][((wm * 8 + a) * 2 + kg) * 512 + lane * 8];
            }
            bf16x8 bfr[2];
#pragma unroll
            for (int bb = 0; bb < 2; bb++)
                bfr[bb] = *(const bf16x8*)
                    &bsh[buf][((wn * 4 + bp * 2 + bb) * 2 + kg) * 512 + lane * 8];
            // front-loaded staging of K-tile t+1 (phases 0-1: 2 subtiles each)
            if (q < 2 && t + 1 < 16) {
#pragma unroll
                for (int v = 0; v < 2; v++) {
                    const int st = wave * 4 + q * 2 + v, mg = st >> 1, kg2 = st & 1;
                    const size_t off = (size_t)(mg * 16 + sm) * CDIM
                                       + (t + 1) * 64 + kg2 * 32 + sc * 8;
                    gld_lds16(Abase + off, &ash[buf ^ 1][st * 512]);
                    gld_lds16(Bbase + off, &bsh[buf ^ 1][st * 512]);
                }
            }
            __builtin_amdgcn_sched_barrier(0);
            __builtin_amdgcn_s_setprio(1);
#pragma unroll
            for (int a = 0; a < 8; a++)
#pragma unroll
                for (int bb = 0; bb < 2; bb++)
                    acc[a][bp * 2 + bb] =
                        MFMA16(af[a], bfr[bb], acc[a][bp * 2 + bb]);
            __builtin_amdgcn_s_setprio(0);
        }
    }

    // ---- epilogue: RoPE for Q/K, transpose-store for V ----
    const int colbase = bnp * 256 + wn * 64;
    const int rr    = colbase >> 10;             // 0=q 1=k 2=v (block-uniform)
    const int nsec  = colbase & 1023;
    const int batch = (bmp * 256) >> 11;
    const int tb    = ((bmp * 256) & 2047) + wm * 128;

    if (rr == 2) {
#pragma unroll
        for (int b = 0; b < 4; b++) {
            const int n = nsec + b * 16 + l16;
            const int h = n >> 6, d = n & 63;
            bf16* vp = Vt + ((size_t)(batch * NH + h) * DH + d) * T_SEQ;
#pragma unroll
            for (int a = 0; a < 8; a++) {
                const int t0 = tb + a * 16 + quad * 4;
                bf16x4 pk4 = { (bf16)acc[a][b][0], (bf16)acc[a][b][1],
                               (bf16)acc[a][b][2], (bf16)acc[a][b][3] };
                *(bf16x4*)(vp + t0) = pk4;
            }
        }
    } else {
        bf16* Dst = (rr == 0) ? Qo : Ko;
        const float scale = (rr == 0) ? Q_SCALE : 1.0f;
#pragma unroll
        for (int b = 0; b < 4; b++) {
            const int n = nsec + b * 16 + l16;
            const int h = n >> 6, d = n & 63;
            const int p = d >> 1, odd = d & 1;
            bf16* dp = Dst + (size_t)(batch * NH + h) * T_SEQ * DH + d;
#pragma unroll
            for (int a = 0; a < 8; a++) {
#pragma unroll
                for (int r = 0; r < 4; r++) {
                    const int trow = tb + a * 16 + quad * 4 + r;
                    const float val = acc[a][b][r];
                    const float partner = __shfl_xor(val, 1);  // pair element d^1
                    const float2 cs = tab[trow * 32 + p];
                    float o = odd ? (partner * cs.y + val * cs.x)
                                  : (val * cs.x - partner * cs.y);
                    dp[(size_t)trow * DH] = (bf16)(o * scale);
                }
            }
        }
    }
}

// ---------------------------------------------------------------------------
// 128x128 GEMM core, BK=64, 2-barrier (r12-proven) — used by gemm_proj
// (proj's grid at 256^2 would be only 128 blocks = half the machine idle).
// ---------------------------------------------------------------------------
#define GEMM_CORE(Abase, Bbase, KDIM)                                            \
    f32x4 acc[4][4] = {};                                                        \
    for (int kk = 0; kk < (KDIM); kk += 64) {                                    \
        __syncthreads();                                                         \
        _Pragma("unroll")                                                        \
        for (int u = 0; u < 4; u++) {                                            \
            const int st = wave * 4 + u, mg = st >> 1, kg = st & 1;              \
            gld_lds16(Abase + (size_t)(mg * 16 + sm) * (KDIM) + kk + kg * 32 + sc * 8, \
                      &ash[st * 512]);                                           \
            gld_lds16(Bbase + (size_t)(mg * 16 + sm) * (KDIM) + kk + kg * 32 + sc * 8, \
                      &bsh[st * 512]);                                           \
        }                                                                        \
        __syncthreads();                                                         \
        _Pragma("unroll")                                                        \
        for (int kg = 0; kg < 2; kg++) {                                         \
            bf16x8 af[4], bfr[4];                                                \
            _Pragma("unroll")                                                    \
            for (int a = 0; a < 4; a++)                                          \
                af[a] = *(const bf16x8*)&ash[((wm * 4 + a) * 2 + kg) * 512 + lane * 8]; \
            _Pragma("unroll")                                                    \
            for (int b = 0; b < 4; b++)                                          \
                bfr[b] = *(const bf16x8*)&bsh[((wn * 4 + b) * 2 + kg) * 512 + lane * 8]; \
            _Pragma("unroll")                                                    \
            for (int a = 0; a < 4; a++)                                          \
                _Pragma("unroll")                                                \
                for (int b = 0; b < 4; b++)                                      \
                    acc[a][b] = MFMA16(af[a], bfr[b], acc[a][b]);                \
        }                                                                        \
    }

// ---------------------------------------------------------------------------
// Out-projection GEMM, fp32 output. Chunked swizzle, bm-fastest (512%8==0).
// ---------------------------------------------------------------------------
__global__ __launch_bounds__(256)
void gemm_proj(const bf16* __restrict__ X, const bf16* __restrict__ W,
               float* __restrict__ Out) {
    __shared__ __align__(16) bf16 ash[16 * 512];
    __shared__ __align__(16) bf16 bsh[16 * 512];
    const int tid = threadIdx.x, lane = tid & 63, wave = tid >> 6;
    const int quad = lane >> 4, l16 = lane & 15;
    const int wm = wave >> 1, wn = wave & 1;
    const int lin = blockIdx.y * 8 + blockIdx.x;         // 0..511
    const int xcd = lin & 7, j = lin >> 3;               // j in [0,64)
    const int bm = xcd * 8 + (j & 7), bn = j >> 3;       // bm-fastest in chunk
    const int sm = lane & 15, sc = lane >> 4;

    const bf16* Abase = X + (size_t)(bm * 128) * CDIM;
    const bf16* Bbase = W + (size_t)(bn * 128) * CDIM;
    GEMM_CORE(Abase, Bbase, CDIM)

#pragma unroll
    for (int b = 0; b < 4; b++) {
        const int n = bn * 128 + wn * 64 + b * 16 + l16;
#pragma unroll
        for (int a = 0; a < 4; a++) {
            const int m = bm * 128 + wm * 64 + a * 16 + quad * 4;
#pragma unroll
            for (int r = 0; r < 4; r++)
                Out[(size_t)(m + r) * CDIM + n] = acc[a][b][r];
        }
    }
}

// ---------------------------------------------------------------------------
// Flash r13 EXACT (322.8us-verified; setprio hurts here — 4 waves are
// barrier-lockstep = m190's null regime): 2 q-tiles per wave, shared K/V LDS
// reads, single-barrier double-buffered staging, bare v_exp_f32,
// permlane32_swap P^T assembly, row-sum li on the MFMA pipe.
// permlane32_swap convention (r10-verified):
//   ret[0] (vdst') = {vdst.lo , src0.lo}; ret[1] (src0') = {vdst.hi , src0.hi}
// ---------------------------------------------------------------------------
__global__ __launch_bounds__(256)
void flash(const bf16* __restrict__ Q, const bf16* __restrict__ K,
           const bf16* __restrict__ Vt, bf16* __restrict__ Y) {
    __shared__ __align__(16) bf16 ksh[2][8 * 512];   // 2 keyblk x 4 dstep
    __shared__ __align__(16) bf16 vsh[2][8 * 512];   // 2 dblk   x 4 kstep
    const int tid = threadIdx.x, lane = tid & 63, wave = tid >> 6;
    const int l32 = lane & 31, hi = lane >> 5;
    const int id = blockIdx.x;                       // 512 blocks
    const int bh = (id & 7) * 8 + ((id >> 3) & 7);   // XCD x -> heads 8x..8x+7
    const int qsb = id >> 6;                         // 0..7 (256-q superblock)
    const size_t kbase = (size_t)bh * T_SEQ * DH;    // Q,K: (B,H,T,D)
    const size_t vbase = (size_t)bh * DH * T_SEQ;    // Vt:  (B,H,D,T)
    const int q0 = qsb * 256 + wave * 32;            // tile A; tile B = q0+128

    // Q B-frags per tile: bq[tq][c][j] = Q[q0+tq*128+l32][c*16 + hi*8 + j]
    bf16x8 bq[2][4];
#pragma unroll
    for (int tq = 0; tq < 2; tq++) {
        const bf16* qp = Q + kbase + (size_t)(q0 + tq * 128 + l32) * DH + hi * 8;
#pragma unroll
        for (int c = 0; c < 4; c++) bq[tq][c] = *(const bf16x8*)(qp + c * 16);
    }

    f32x16 oT[2][2] = {};
    f32x16 lf[2] = {};       // li via MFMA: every elem = sum_k P[k][q]
    bf16x8 onesf;
#pragma unroll
    for (int j = 0; j < 8; j++) onesf[j] = (bf16)1.0f;

    // Stage 64 keys x 64 d of K and V(t) into buffer buf_.
#define STAGE(buf_, kt_) do {                                              \
        if (wave < 2) {                                                    \
            _Pragma("unroll")                                              \
            for (int u = 0; u < 4; u++) {                                  \
                const int s = wave * 4 + u, kb = s >> 2, c = s & 3;        \
                gld_lds16(K + kbase + (size_t)((kt_) + kb * 32 + l32) * DH \
                              + c * 16 + hi * 8,                           \
                          &ksh[buf_][s * 512]);                            \
            }                                                              \
        } else {                                                           \
            _Pragma("unroll")                                              \
            for (int u = 0; u < 4; u++) {                                  \
                const int s = (wave - 2) * 4 + u, db = s >> 2, kc = s & 3; \
                gld_lds16(Vt + vbase + (size_t)(db * 32 + l32) * T_SEQ     \
                              + (kt_) + kc * 16 + hi * 8,                  \
                          &vsh[buf_][s * 512]);                            \
            }                                                              \
        }                                                                  \
    } while (0)

    STAGE(0, 0);
    int ib = 0;
    for (int kt = 0; kt < T_SEQ; kt += 64, ib ^= 1) {
        __syncthreads();   // publishes buf ib; prior reads of ib^1 all done
        if (kt + 64 < T_SEQ) STAGE(ib ^ 1, kt + 64);

#pragma unroll
        for (int kb = 0; kb < 2; kb++) {
            // S^T for 32 keys x (2 x 32 q) — K-frag shared by both tiles
            f32x16 s0 = {}, s1 = {};
#pragma unroll
            for (int c = 0; c < 4; c++) {
                const bf16x8 a = *(const bf16x8*)&ksh[ib][(kb * 4 + c) * 512 + lane * 8];
                s0 = MFMA32(a, bq[0][c], s0);
                s1 = MFMA32(a, bq[1][c], s1);
            }
            // bare v_exp_f32 (log2e pre-folded) + bf16x2 pack, both tiles
            uint P[2][8];
#pragma unroll
            for (int w = 0; w < 8; w++) {
                P[0][w] = pack_bf16(fexp2(s0[2 * w]), fexp2(s0[2 * w + 1]));
                P[1][w] = pack_bf16(fexp2(s1[2 * w]), fexp2(s1[2 * w + 1]));
            }
            // PV per 16-key step; V-frags shared by both tiles.
            // swap(P0,P2): ret[0]={P0.lo,P2.lo}=u[0], ret[1]={P0.hi,P2.hi}=u[2]
#pragma unroll
            for (int t = 0; t < 2; t++) {
                const int kc = kb * 2 + t;
                bf16x8 vv[2];
#pragma unroll
                for (int db = 0; db < 2; db++)
                    vv[db] = *(const bf16x8*)&vsh[ib][(db * 4 + kc) * 512 + lane * 8];
#pragma unroll
                for (int tq = 0; tq < 2; tq++) {
                    const uintx2 rA = __builtin_amdgcn_permlane32_swap(
                        P[tq][4 * t + 0], P[tq][4 * t + 2], false, false);
                    const uintx2 rB = __builtin_amdgcn_permlane32_swap(
                        P[tq][4 * t + 1], P[tq][4 * t + 3], false, false);
                    union { uint u[4]; bf16x8 v; } bP;
                    bP.u[0] = rA[0]; bP.u[1] = rB[0];
                    bP.u[2] = rA[1]; bP.u[3] = rB[1];
                    lf[tq] = MFMA32(onesf, bP.v, lf[tq]);   // row-sum on MFMA pipe
#pragma unroll
                    for (int db = 0; db < 2; db++)
                        oT[tq][db] = MFMA32(vv[db], bP.v, oT[tq][db]);
                }
            }
        }
    }
#undef STAGE

    // O^T: d = db*32 + (reg&3) + 8*(reg>>2) + 4*hi, q = l32. Y is (B,T,C).
    const int b = bh >> 4, h = bh & 15;
#pragma unroll
    for (int tq = 0; tq < 2; tq++) {
        const float inv = 1.0f / lf[tq][0];
        const size_t yrow =
            ((size_t)b * T_SEQ + q0 + tq * 128 + l32) * CDIM + h * DH;
#pragma unroll
        for (int db = 0; db < 2; db++)
#pragma unroll
            for (int rg = 0; rg < 4; rg++) {
                bf16x4 o4 = { (bf16)(oT[tq][db][rg * 4 + 0] * inv),
                              (bf16)(oT[tq][db][rg * 4 + 1] * inv),
                              (bf16)(oT[tq][db][rg * 4 + 2] * inv),
                              (bf16)(oT[tq][db][rg * 4 + 3] * inv) };
                *(bf16x4*)(Y + yrow + db * 32 + 8 * rg + 4 * hi) = o4;
            }
    }
}

// ---------------------------------------------------------------------------
extern "C" void kernel_launch(void* const* d_in, const int* in_sizes, int n_in,
                              void* d_out, int out_size, void* d_ws, size_t ws_size,
                              hipStream_t stream) {
    const float* x      = (const float*)d_in[0];   // (4,2048,1024) fp32
    const float* w_attn = (const float*)d_in[1];   // (3072,1024) fp32
    const float* w_proj = (const float*)d_in[2];   // (1024,1024) fp32
    float* out = (float*)d_out;                    // (4,2048,1024) fp32

    bf16* ws = (bf16*)d_ws;
    const size_t SZ = (size_t)4 * NH * T_SEQ * DH;   // 8388608
    bf16* Xb  = ws;
    bf16* Wab = Xb + SZ;                             // 3145728
    bf16* Wpb = Wab + 3145728;                       // 1048576
    bf16* Qb  = Wpb + 1048576;
    bf16* Kb  = Qb + SZ;
    bf16* Vtb = Kb + SZ;                             // transposed (B,H,D,T)
    bf16* Yb  = Vtb + SZ;
    float2* tab = (float2*)(Yb + SZ);                // 2048*32 float2 = 512 KB

    prologue<<<6400, 256, 0, stream>>>(x, w_attn, w_proj, Xb, Wab, Wpb, tab);
    gemm_qkv<<<dim3(12, 32), 512, 0, stream>>>(Xb, Wab, Qb, Kb, Vtb, tab);
    flash<<<512, 256, 0, stream>>>(Qb, Kb, Vtb, Yb);
    gemm_proj<<<dim3(8, 64), 256, 0, stream>>>(Yb, Wpb, out);
}